// Round 3
// baseline (1372.797 us; speedup 1.0000x reference)
//
#include <hip/hip_runtime.h>
#include <hip/hip_bf16.h>
#include <math.h>

namespace {
constexpr int Bc = 64, Nc = 2048, Dc = 256, Hc = 8, DHc = 32, Sc = 10;
constexpr float kNeg = -1000000000.0f;
constexpr float kClip = 10.0f;
constexpr float kScale = 0.17677669529663687f;   // 1/sqrt(32)
constexpr float kScale2 = 0.0625f;               // 1/sqrt(256)
}

// ---- h_mean partials ----
__global__ __launch_bounds__(256) void k_hmean_part(const float* __restrict__ enc,
                                                    float* __restrict__ hpart) {
  int b = blockIdx.x >> 3, c = blockIdx.x & 7, d = threadIdx.x;
  const float* p = enc + ((size_t)b * Nc + c * 256) * Dc + d;
  float s = 0.f;
  for (int n = 0; n < 256; ++n) s += p[(size_t)n * Dc];
  hpart[(size_t)blockIdx.x * Dc + d] = s;
}

__global__ __launch_bounds__(256) void k_hmean_red(const float* __restrict__ hpart,
                                                   float* __restrict__ hmean) {
  int b = blockIdx.x, d = threadIdx.x;
  float s = 0.f;
  for (int c = 0; c < 8; ++c) s += hpart[(size_t)(b * 8 + c) * Dc + d];
  hmean[b * Dc + d] = s * (1.0f / Nc);
}

// ---- q = hmean@Wq^T + bq ; g[b,h,:] = q_h^T Wk_h ; c[b,h] = q_h . bk_h ----
__global__ __launch_bounds__(256) void k_qgc(const float* __restrict__ hmean,
                                             const float* __restrict__ w_in,
                                             const float* __restrict__ b_in,
                                             float* __restrict__ g, float* __restrict__ c) {
  int b = blockIdx.x, t = threadIdx.x;
  __shared__ float hm[Dc];
  __shared__ float qsh[Dc];
  hm[t] = hmean[b * Dc + t];
  __syncthreads();
  {
    const float* row = w_in + (size_t)t * Dc;  // Wq row t
    float acc = b_in[t];
    for (int d = 0; d < Dc; ++d) acc += row[d] * hm[d];
    qsh[t] = acc;
  }
  __syncthreads();
  for (int h = 0; h < Hc; ++h) {
    float acc = 0.f;
    const float* wk = w_in + (size_t)(Dc + h * DHc) * Dc + t;  // Wk rows, col t
    const float* qh = qsh + h * DHc;
    #pragma unroll 8
    for (int i = 0; i < DHc; ++i) acc += qh[i] * wk[(size_t)i * Dc];
    g[((size_t)b * Hc + h) * Dc + t] = acc;
  }
  if (t < Hc) {
    float acc = 0.f;
    for (int i = 0; i < DHc; ++i) acc += qsh[t * DHc + i] * b_in[Dc + t * DHc + i];
    c[b * Hc + t] = acc;
  }
}

// ---- setup: M1 = sha_wq @ out_w ; m1b = sha_wq @ out_b ----
__global__ __launch_bounds__(256) void k_A1(const float* __restrict__ swq,
                                            const float* __restrict__ ow,
                                            const float* __restrict__ ob,
                                            float* __restrict__ M1, float* __restrict__ m1b) {
  int i = blockIdx.x, e = threadIdx.x;
  __shared__ float row[Dc];
  __shared__ float red[256];
  row[e] = swq[(size_t)i * Dc + e];
  __syncthreads();
  float acc = 0.f;
  #pragma unroll 4
  for (int k = 0; k < Dc; ++k) acc += row[k] * ow[(size_t)k * Dc + e];
  M1[(size_t)i * Dc + e] = acc;
  red[e] = row[e] * ob[e];
  __syncthreads();
  for (int off = 128; off >= 1; off >>= 1) {
    if (e < off) red[e] += red[e + off];
    __syncthreads();
  }
  if (e == 0) m1b[i] = red[0];
}

// ---- setup: A = sha_wk^T @ M1 ; cvec = A@bv + sha_wk^T@m1b ----
__global__ __launch_bounds__(256) void k_A2(const float* __restrict__ swk,
                                            const float* __restrict__ M1,
                                            const float* __restrict__ m1b,
                                            const float* __restrict__ b_in,
                                            float* __restrict__ Aout, float* __restrict__ cvec) {
  int d = blockIdx.x, e = threadIdx.x;
  __shared__ float col[Dc];
  __shared__ float red[256];
  col[e] = swk[(size_t)e * Dc + d];
  __syncthreads();
  float acc = 0.f;
  #pragma unroll 4
  for (int k = 0; k < Dc; ++k) acc += col[k] * M1[(size_t)k * Dc + e];
  Aout[(size_t)d * Dc + e] = acc;
  red[e] = acc * b_in[2 * Dc + e] + col[e] * m1b[e];
  __syncthreads();
  for (int off = 128; off >= 1; off >>= 1) {
    if (e < off) red[e] += red[e + off];
    __syncthreads();
  }
  if (e == 0) cvec[d] = red[0];
}

// ---- setup: BT[(h*256+e)*256+d] = sum_i A[d][h*32+i] * Wv[h*32+i][e] ----
__global__ __launch_bounds__(256) void k_A3(const float* __restrict__ Aout,
                                            const float* __restrict__ w_in,
                                            float* __restrict__ BT) {
  int h = blockIdx.x >> 3, et = blockIdx.x & 7, d = threadIdx.x;
  float arow[DHc];
  #pragma unroll
  for (int i = 0; i < DHc; ++i) arow[i] = Aout[(size_t)d * Dc + h * DHc + i];
  __shared__ float wv[DHc][DHc];
  for (int k = threadIdx.x; k < DHc * DHc; k += 256) {
    int i = k >> 5, j = k & 31;
    wv[i][j] = w_in[(size_t)(2 * Dc + h * DHc + i) * Dc + et * DHc + j];
  }
  __syncthreads();
  for (int j = 0; j < DHc; ++j) {
    float acc = 0.f;
    #pragma unroll
    for (int i = 0; i < DHc; ++i) acc += arow[i] * wv[i][j];
    BT[((size_t)h * Dc + et * DHc + j) * Dc + d] = acc;
  }
}

// ---- scores: row-per-thread, no syncs after staging ----
__global__ __launch_bounds__(256) void k_scores(const float* __restrict__ enc,
                                                const float* __restrict__ g,
                                                const float* __restrict__ c,
                                                float* __restrict__ s) {
  int b = blockIdx.x >> 3, nt = blockIdx.x & 7, t = threadIdx.x;
  int n = nt * 256 + t;
  __shared__ float gsm[Hc * Dc];
  __shared__ float csm[Hc];
  for (int k = t; k < Hc * Dc; k += 256) gsm[k] = g[(size_t)b * Hc * Dc + k];
  if (t < Hc) csm[t] = c[b * Hc + t];
  __syncthreads();
  const float4* row = reinterpret_cast<const float4*>(enc + ((size_t)b * Nc + n) * Dc);
  float acc[Hc] = {};
  #pragma unroll 8
  for (int d4 = 0; d4 < 64; ++d4) {
    const float4 e = row[d4];
    #pragma unroll
    for (int h = 0; h < Hc; ++h) {
      const float4 g4 = *reinterpret_cast<const float4*>(gsm + h * Dc + d4 * 4);
      acc[h] += e.x * g4.x + e.y * g4.y + e.z * g4.z + e.w * g4.w;
    }
  }
  #pragma unroll
  for (int h = 0; h < Hc; ++h)
    s[((size_t)b * Hc + h) * Nc + n] = kScale * (acc[h] + csm[h]);
}

// ---- fused rowmax + exp + rowsum per (b,h) ----
__global__ __launch_bounds__(256) void k_smax(const float* __restrict__ s,
                                              float* __restrict__ w, float* __restrict__ W0) {
  int bh = blockIdx.x, t = threadIdx.x;
  __shared__ float red[256];
  float lv[8];
  float m = -3.0e38f;
  #pragma unroll
  for (int q = 0; q < 8; ++q) {
    lv[q] = s[(size_t)bh * Nc + q * 256 + t];
    m = fmaxf(m, lv[q]);
  }
  red[t] = m;
  __syncthreads();
  for (int off = 128; off >= 1; off >>= 1) {
    if (t < off) red[t] = fmaxf(red[t], red[t + off]);
    __syncthreads();
  }
  m = red[0];
  __syncthreads();
  float ssum = 0.f;
  #pragma unroll
  for (int q = 0; q < 8; ++q) {
    float e = expf(lv[q] - m);
    w[(size_t)bh * Nc + q * 256 + t] = e;
    ssum += e;
  }
  red[t] = ssum;
  __syncthreads();
  for (int off = 128; off >= 1; off >>= 1) {
    if (t < off) red[t] += red[t + off];
    __syncthreads();
  }
  if (t == 0) W0[bh] = red[0];
}

// ---- S0 partials ----
__global__ __launch_bounds__(256) void k_S0part(const float* __restrict__ enc,
                                                const float* __restrict__ w,
                                                float* __restrict__ Spart) {
  int b = blockIdx.x >> 3, cid = blockIdx.x & 7, t = threadIdx.x;
  __shared__ float wsm[Hc * 256];
  for (int k = t; k < Hc * 256; k += 256) {
    int h = k >> 8, ni = k & 255;
    wsm[k] = w[((size_t)b * Hc + h) * Nc + cid * 256 + ni];
  }
  __syncthreads();
  float acc[Hc] = {};
  const float* ep = enc + ((size_t)b * Nc + cid * 256) * Dc + t;
  for (int ni = 0; ni < 256; ++ni) {
    float ev = ep[(size_t)ni * Dc];
    #pragma unroll
    for (int h = 0; h < Hc; ++h) acc[h] += wsm[h * 256 + ni] * ev;
  }
  #pragma unroll
  for (int h = 0; h < Hc; ++h)
    Spart[(((size_t)b * 8 + cid) * Hc + h) * Dc + t] = acc[h];
}

__global__ __launch_bounds__(256) void k_S0red(const float* __restrict__ Spart,
                                               float* __restrict__ Sacc) {
  int b = blockIdx.x >> 3, h = blockIdx.x & 7, t = threadIdx.x;
  float acc = 0.f;
  for (int cid = 0; cid < 8; ++cid)
    acc += Spart[(((size_t)b * 8 + cid) * Hc + h) * Dc + t];
  Sacc[((size_t)b * Hc + h) * Dc + t] = acc;
}

// ---- fused select(t-1) + chain(t): one block per b ----
__global__ __launch_bounds__(256) void k_selchain(const float* __restrict__ u,
                                                  int* __restrict__ mask, int* __restrict__ hist,
                                                  float* __restrict__ out,
                                                  const float* __restrict__ Sacc,
                                                  const float* __restrict__ W0,
                                                  const float* __restrict__ w,
                                                  const float* __restrict__ enc,
                                                  const float* __restrict__ BT,
                                                  const float* __restrict__ cvec,
                                                  float* __restrict__ r, int tstep) {
  int b = blockIdx.x, t = threadIdx.x;
  __shared__ float sh[Hc * Dc];
  __shared__ float red[256];
  __shared__ int redi[256];
  __shared__ int histsh[16];
  if (t < 16) histsh[t] = hist[b * 16 + t];
  __syncthreads();

  if (tstep > 0) {
    int sel_t = tstep - 1;
    float uval[8];
    float lmax = -3.0e38f;
    int lidx = 0;
    #pragma unroll
    for (int q = 0; q < 8; ++q) {
      int n = t + q * 256;
      float v = u[(size_t)b * Nc + n];
      if (mask[b * Nc + n]) v = kNeg;
      uval[q] = v;
      if (v > lmax) { lmax = v; lidx = n; }
    }
    red[t] = lmax; redi[t] = lidx;
    __syncthreads();
    for (int off = 128; off >= 1; off >>= 1) {
      if (t < off) {
        float o = red[t + off]; int oi = redi[t + off];
        if (o > red[t] || (o == red[t] && oi < redi[t])) { red[t] = o; redi[t] = oi; }
      }
      __syncthreads();
    }
    float mu = red[0];
    int gidx = redi[0];
    __syncthreads();
    float ssum = 0.f;
    #pragma unroll
    for (int q = 0; q < 8; ++q) ssum += expf(uval[q] - mu);
    red[t] = ssum;
    __syncthreads();
    for (int off = 128; off >= 1; off >>= 1) {
      if (t < off) red[t] += red[t + off];
      __syncthreads();
    }
    float Z = red[0];
    float lse = mu + logf(Z);
    __syncthreads();
    float ent = 0.f;
    #pragma unroll
    for (int q = 0; q < 8; ++q) {
      float logp = uval[q] - lse;
      float p = expf(logp);
      if (p > 0.f) ent -= p * logp;
    }
    red[t] = ent;
    __syncthreads();
    for (int off = 128; off >= 1; off >>= 1) {
      if (t < off) red[t] += red[t + off];
      __syncthreads();
    }
    if (t == 0) {
      float enttot = red[0];
      float pi = expf(u[(size_t)b * Nc + gidx] - lse);
      out[b * Sc + sel_t] = (float)gidx;
      out[Bc * Sc + b * Sc + sel_t] = pi;
      if (sel_t == 0) out[2 * Bc * Sc + b] = enttot;
      else out[2 * Bc * Sc + b] += enttot;
      hist[b * 16 + sel_t] = gidx;
      histsh[sel_t] = gidx;
      mask[b * Nc + gidx] = 1;
    }
    __syncthreads();
  }

  // chain: sh[h][t] = (Sacc - removals)/W
  #pragma unroll
  for (int h = 0; h < Hc; ++h) {
    float se = Sacc[((size_t)b * Hc + h) * Dc + t];
    float Wh = W0[b * Hc + h];
    for (int tt = 0; tt < tstep; ++tt) {
      int j = histsh[tt];
      float wv = w[((size_t)b * Hc + h) * Nc + j];
      se -= wv * enc[((size_t)b * Nc + j) * Dc + t];
      Wh -= wv;
    }
    sh[h * Dc + t] = se / Wh;
  }
  __syncthreads();
  float acc = cvec[t];
  const float* bt = BT + t;
  #pragma unroll 8
  for (int k = 0; k < Hc * Dc; ++k) acc += bt[(size_t)k * Dc] * sh[k];
  r[b * Dc + t] = acc;
}

// ---- u scores: row-per-thread, no syncs after staging ----
__global__ __launch_bounds__(256) void k_uscore(const float* __restrict__ enc,
                                                const float* __restrict__ r,
                                                float* __restrict__ u) {
  int b = blockIdx.x >> 3, nt = blockIdx.x & 7, t = threadIdx.x;
  int n = nt * 256 + t;
  __shared__ __align__(16) float rsm[Dc];
  rsm[t] = r[b * Dc + t];
  __syncthreads();
  const float4* row = reinterpret_cast<const float4*>(enc + ((size_t)b * Nc + n) * Dc);
  float acc = 0.f;
  #pragma unroll 16
  for (int d4 = 0; d4 < 64; ++d4) {
    const float4 e = row[d4];
    const float4 rr = *reinterpret_cast<const float4*>(rsm + d4 * 4);
    acc += e.x * rr.x + e.y * rr.y + e.z * rr.z + e.w * rr.w;
  }
  u[(size_t)b * Nc + n] = kClip * tanhf(kScale2 * acc);
}

// ---- final select (step Sc-1) ----
__global__ __launch_bounds__(256) void k_selfinal(const float* __restrict__ u,
                                                  int* __restrict__ mask,
                                                  float* __restrict__ out) {
  int b = blockIdx.x, t = threadIdx.x;
  __shared__ float red[256];
  __shared__ int redi[256];
  float uval[8];
  float lmax = -3.0e38f;
  int lidx = 0;
  #pragma unroll
  for (int q = 0; q < 8; ++q) {
    int n = t + q * 256;
    float v = u[(size_t)b * Nc + n];
    if (mask[b * Nc + n]) v = kNeg;
    uval[q] = v;
    if (v > lmax) { lmax = v; lidx = n; }
  }
  red[t] = lmax; redi[t] = lidx;
  __syncthreads();
  for (int off = 128; off >= 1; off >>= 1) {
    if (t < off) {
      float o = red[t + off]; int oi = redi[t + off];
      if (o > red[t] || (o == red[t] && oi < redi[t])) { red[t] = o; redi[t] = oi; }
    }
    __syncthreads();
  }
  float mu = red[0];
  int gidx = redi[0];
  __syncthreads();
  float ssum = 0.f;
  #pragma unroll
  for (int q = 0; q < 8; ++q) ssum += expf(uval[q] - mu);
  red[t] = ssum;
  __syncthreads();
  for (int off = 128; off >= 1; off >>= 1) {
    if (t < off) red[t] += red[t + off];
    __syncthreads();
  }
  float Z = red[0];
  float lse = mu + logf(Z);
  __syncthreads();
  float ent = 0.f;
  #pragma unroll
  for (int q = 0; q < 8; ++q) {
    float logp = uval[q] - lse;
    float p = expf(logp);
    if (p > 0.f) ent -= p * logp;
  }
  red[t] = ent;
  __syncthreads();
  for (int off = 128; off >= 1; off >>= 1) {
    if (t < off) red[t] += red[t + off];
    __syncthreads();
  }
  if (t == 0) {
    float enttot = red[0];
    float pi = expf(u[(size_t)b * Nc + gidx] - lse);
    out[b * Sc + (Sc - 1)] = (float)gidx;
    out[Bc * Sc + b * Sc + (Sc - 1)] = pi;
    out[2 * Bc * Sc + b] += enttot;
  }
}

extern "C" void kernel_launch(void* const* d_in, const int* in_sizes, int n_in,
                              void* d_out, int out_size, void* d_ws, size_t ws_size,
                              hipStream_t stream) {
  (void)in_sizes; (void)n_in; (void)out_size; (void)ws_size;
  const float* enc  = (const float*)d_in[0];
  const float* in_w = (const float*)d_in[1];
  const float* in_b = (const float*)d_in[2];
  const float* ow   = (const float*)d_in[3];
  const float* ob   = (const float*)d_in[4];
  const float* swq  = (const float*)d_in[5];
  const float* swk  = (const float*)d_in[6];
  float* out = (float*)d_out;

  float* ws = (float*)d_ws;
  size_t off = 0;
  auto alloc = [&](size_t n) { float* p = ws + off; off += n; return p; };
  float* hpart = alloc((size_t)Bc * 8 * Dc);
  float* hmean = alloc((size_t)Bc * Dc);
  float* g     = alloc((size_t)Bc * Hc * Dc);
  float* c     = alloc((size_t)Bc * Hc);
  float* s     = alloc((size_t)Bc * Hc * Nc);
  float* w     = alloc((size_t)Bc * Hc * Nc);
  float* W0    = alloc((size_t)Bc * Hc);
  float* Spart = alloc((size_t)Bc * 8 * Hc * Dc);
  float* Sacc  = alloc((size_t)Bc * Hc * Dc);
  float* M1    = alloc((size_t)Dc * Dc);
  float* m1b   = alloc(Dc);
  float* Aout  = alloc((size_t)Dc * Dc);
  float* cvec  = alloc(Dc);
  float* BT    = alloc((size_t)Hc * Dc * Dc);
  float* r     = alloc((size_t)Bc * Dc);
  float* u     = alloc((size_t)Bc * Nc);
  int* mask    = (int*)alloc((size_t)Bc * Nc);
  int* hist    = (int*)alloc((size_t)Bc * 16);

  k_hmean_part<<<Bc * 8, 256, 0, stream>>>(enc, hpart);
  k_hmean_red<<<Bc, 256, 0, stream>>>(hpart, hmean);
  k_qgc<<<Bc, 256, 0, stream>>>(hmean, in_w, in_b, g, c);
  k_A1<<<Dc, 256, 0, stream>>>(swq, ow, ob, M1, m1b);
  k_A2<<<Dc, 256, 0, stream>>>(swk, M1, m1b, in_b, Aout, cvec);
  k_A3<<<Hc * 8, 256, 0, stream>>>(Aout, in_w, BT);
  k_scores<<<Bc * 8, 256, 0, stream>>>(enc, g, c, s);
  k_smax<<<Bc * Hc, 256, 0, stream>>>(s, w, W0);
  k_S0part<<<Bc * 8, 256, 0, stream>>>(enc, w, Spart);
  k_S0red<<<Bc * Hc, 256, 0, stream>>>(Spart, Sacc);
  hipMemsetAsync(mask, 0, (size_t)Bc * Nc * sizeof(int), stream);

  for (int t = 0; t < Sc; ++t) {
    k_selchain<<<Bc, 256, 0, stream>>>(u, mask, hist, out, Sacc, W0, w, enc, BT, cvec, r, t);
    k_uscore<<<Bc * 8, 256, 0, stream>>>(enc, r, u);
  }
  k_selfinal<<<Bc, 256, 0, stream>>>(u, mask, out);
}

// Round 4
// 566.118 us; speedup vs baseline: 2.4249x; 2.4249x over previous
//
#include <hip/hip_runtime.h>
#include <hip/hip_bf16.h>
#include <math.h>

namespace {
constexpr int Bc = 64, Nc = 2048, Dc = 256, Hc = 8, DHc = 32, Sc = 10;
constexpr float kNeg = -1000000000.0f;
constexpr float kClip = 10.0f;
constexpr float kScale = 0.17677669529663687f;   // 1/sqrt(32)
constexpr float kScale2 = 0.0625f;               // 1/sqrt(256)
}

// ---- h_mean partials ----
__global__ __launch_bounds__(256) void k_hmean_part(const float* __restrict__ enc,
                                                    float* __restrict__ hpart) {
  int b = blockIdx.x >> 3, c = blockIdx.x & 7, d = threadIdx.x;
  const float* p = enc + ((size_t)b * Nc + c * 256) * Dc + d;
  float s = 0.f;
  for (int n = 0; n < 256; ++n) s += p[(size_t)n * Dc];
  hpart[(size_t)blockIdx.x * Dc + d] = s;
}

// ---- qgc (folds hmean reduction): q, g, c ----
__global__ __launch_bounds__(256) void k_qgc(const float* __restrict__ hpart,
                                             const float* __restrict__ w_in,
                                             const float* __restrict__ b_in,
                                             float* __restrict__ g, float* __restrict__ c) {
  int b = blockIdx.x, t = threadIdx.x;
  __shared__ float hm[Dc];
  __shared__ float qsh[Dc];
  {
    float s = 0.f;
    for (int cc = 0; cc < 8; ++cc) s += hpart[(size_t)(b * 8 + cc) * Dc + t];
    hm[t] = s * (1.0f / Nc);
  }
  __syncthreads();
  {
    const float* row = w_in + (size_t)t * Dc;  // Wq row t
    float acc = b_in[t];
    for (int d = 0; d < Dc; ++d) acc += row[d] * hm[d];
    qsh[t] = acc;
  }
  __syncthreads();
  for (int h = 0; h < Hc; ++h) {
    float acc = 0.f;
    const float* wk = w_in + (size_t)(Dc + h * DHc) * Dc + t;  // Wk rows, col t
    const float* qh = qsh + h * DHc;
    #pragma unroll 8
    for (int i = 0; i < DHc; ++i) acc += qh[i] * wk[(size_t)i * Dc];
    g[((size_t)b * Hc + h) * Dc + t] = acc;
  }
  if (t < Hc) {
    float acc = 0.f;
    for (int i = 0; i < DHc; ++i) acc += qsh[t * DHc + i] * b_in[Dc + t * DHc + i];
    c[b * Hc + t] = acc;
  }
}

// ---- setup: M1 = sha_wq @ out_w ; m1b = sha_wq @ out_b ----
__global__ __launch_bounds__(256) void k_A1(const float* __restrict__ swq,
                                            const float* __restrict__ ow,
                                            const float* __restrict__ ob,
                                            float* __restrict__ M1, float* __restrict__ m1b) {
  int i = blockIdx.x, e = threadIdx.x;
  __shared__ float row[Dc];
  __shared__ float red[256];
  row[e] = swq[(size_t)i * Dc + e];
  __syncthreads();
  float acc = 0.f;
  #pragma unroll 4
  for (int k = 0; k < Dc; ++k) acc += row[k] * ow[(size_t)k * Dc + e];
  M1[(size_t)i * Dc + e] = acc;
  red[e] = row[e] * ob[e];
  __syncthreads();
  for (int off = 128; off >= 1; off >>= 1) {
    if (e < off) red[e] += red[e + off];
    __syncthreads();
  }
  if (e == 0) m1b[i] = red[0];
}

// ---- setup: A = sha_wk^T @ M1 ; cvec = A@bv + sha_wk^T@m1b ----
__global__ __launch_bounds__(256) void k_A2(const float* __restrict__ swk,
                                            const float* __restrict__ M1,
                                            const float* __restrict__ m1b,
                                            const float* __restrict__ b_in,
                                            float* __restrict__ Aout, float* __restrict__ cvec) {
  int d = blockIdx.x, e = threadIdx.x;
  __shared__ float col[Dc];
  __shared__ float red[256];
  col[e] = swk[(size_t)e * Dc + d];
  __syncthreads();
  float acc = 0.f;
  #pragma unroll 4
  for (int k = 0; k < Dc; ++k) acc += col[k] * M1[(size_t)k * Dc + e];
  Aout[(size_t)d * Dc + e] = acc;
  red[e] = acc * b_in[2 * Dc + e] + col[e] * m1b[e];
  __syncthreads();
  for (int off = 128; off >= 1; off >>= 1) {
    if (e < off) red[e] += red[e + off];
    __syncthreads();
  }
  if (e == 0) cvec[d] = red[0];
}

// ---- setup: BT[(h*256+e)*256+d] = sum_i A[d][h*32+i] * Wv[h*32+i][e] ----
__global__ __launch_bounds__(256) void k_A3(const float* __restrict__ Aout,
                                            const float* __restrict__ w_in,
                                            float* __restrict__ BT) {
  int h = blockIdx.x >> 3, et = blockIdx.x & 7, d = threadIdx.x;
  float arow[DHc];
  #pragma unroll
  for (int i = 0; i < DHc; ++i) arow[i] = Aout[(size_t)d * Dc + h * DHc + i];
  __shared__ float wv[DHc][DHc];
  for (int k = threadIdx.x; k < DHc * DHc; k += 256) {
    int i = k >> 5, j = k & 31;
    wv[i][j] = w_in[(size_t)(2 * Dc + h * DHc + i) * Dc + et * DHc + j];
  }
  __syncthreads();
  for (int j = 0; j < DHc; ++j) {
    float acc = 0.f;
    #pragma unroll
    for (int i = 0; i < DHc; ++i) acc += arow[i] * wv[i][j];
    BT[((size_t)h * Dc + et * DHc + j) * Dc + d] = acc;
  }
}

// ---- scores: row-per-thread ----
__global__ __launch_bounds__(256) void k_scores(const float* __restrict__ enc,
                                                const float* __restrict__ g,
                                                const float* __restrict__ c,
                                                float* __restrict__ s) {
  int b = blockIdx.x >> 3, nt = blockIdx.x & 7, t = threadIdx.x;
  int n = nt * 256 + t;
  __shared__ float gsm[Hc * Dc];
  __shared__ float csm[Hc];
  for (int k = t; k < Hc * Dc; k += 256) gsm[k] = g[(size_t)b * Hc * Dc + k];
  if (t < Hc) csm[t] = c[b * Hc + t];
  __syncthreads();
  const float4* row = reinterpret_cast<const float4*>(enc + ((size_t)b * Nc + n) * Dc);
  float acc[Hc] = {};
  #pragma unroll 8
  for (int d4 = 0; d4 < 64; ++d4) {
    const float4 e = row[d4];
    #pragma unroll
    for (int h = 0; h < Hc; ++h) {
      const float4 g4 = *reinterpret_cast<const float4*>(gsm + h * Dc + d4 * 4);
      acc[h] += e.x * g4.x + e.y * g4.y + e.z * g4.z + e.w * g4.w;
    }
  }
  #pragma unroll
  for (int h = 0; h < Hc; ++h)
    s[((size_t)b * Hc + h) * Nc + n] = kScale * (acc[h] + csm[h]);
}

// ---- rowmax per (b,h) ----
__global__ __launch_bounds__(256) void k_rowmax(const float* __restrict__ s,
                                                float* __restrict__ mrow) {
  int bh = blockIdx.x, t = threadIdx.x;
  __shared__ float red[256];
  float m = -3.0e38f;
  #pragma unroll
  for (int q = 0; q < 8; ++q) m = fmaxf(m, s[(size_t)bh * Nc + q * 256 + t]);
  red[t] = m;
  __syncthreads();
  for (int off = 128; off >= 1; off >>= 1) {
    if (t < off) red[t] = fmaxf(red[t], red[t + off]);
    __syncthreads();
  }
  if (t == 0) mrow[bh] = red[0];
}

// ---- S0 partials (+exp fold: w = exp(s-m)) ----
__global__ __launch_bounds__(256) void k_S0part(const float* __restrict__ enc,
                                                const float* __restrict__ s,
                                                const float* __restrict__ mrow,
                                                float* __restrict__ w,
                                                float* __restrict__ Spart) {
  int b = blockIdx.x >> 3, cid = blockIdx.x & 7, t = threadIdx.x;
  __shared__ float wsm[Hc * 256];
  #pragma unroll
  for (int h = 0; h < Hc; ++h) {
    float m = mrow[b * Hc + h];
    float e = expf(s[((size_t)b * Hc + h) * Nc + cid * 256 + t] - m);
    wsm[h * 256 + t] = e;
    w[((size_t)b * Hc + h) * Nc + cid * 256 + t] = e;
  }
  __syncthreads();
  float acc[Hc] = {};
  const float* ep = enc + ((size_t)b * Nc + cid * 256) * Dc + t;
  for (int ni = 0; ni < 256; ++ni) {
    float ev = ep[(size_t)ni * Dc];
    #pragma unroll
    for (int h = 0; h < Hc; ++h) acc[h] += wsm[h * 256 + ni] * ev;
  }
  #pragma unroll
  for (int h = 0; h < Hc; ++h)
    Spart[(((size_t)b * 8 + cid) * Hc + h) * Dc + t] = acc[h];
}

// ---- S0 reduce + W0 = sum_n w ----
__global__ __launch_bounds__(256) void k_S0red(const float* __restrict__ Spart,
                                               const float* __restrict__ w,
                                               float* __restrict__ Sacc,
                                               float* __restrict__ W0) {
  int b = blockIdx.x >> 3, h = blockIdx.x & 7, t = threadIdx.x;
  __shared__ float red[256];
  float acc = 0.f;
  for (int cid = 0; cid < 8; ++cid)
    acc += Spart[(((size_t)b * 8 + cid) * Hc + h) * Dc + t];
  Sacc[((size_t)b * Hc + h) * Dc + t] = acc;
  float ws = 0.f;
  #pragma unroll
  for (int q = 0; q < 8; ++q) ws += w[((size_t)b * Hc + h) * Nc + q * 256 + t];
  red[t] = ws;
  __syncthreads();
  for (int off = 128; off >= 1; off >>= 1) {
    if (t < off) red[t] += red[t + off];
    __syncthreads();
  }
  if (t == 0) W0[b * Hc + h] = red[0];
}

// ---- shared select core: masked log-softmax + argmax + entropy ----
__device__ __forceinline__ void select_core(const float* __restrict__ ub,
                                            const int* histsh, int nhist, int t,
                                            float* red, int* redi,
                                            int& gidx_out, float& lse_out, float& ent_out) {
  float uval[8];
  float lmax = -3.0e38f;
  int lidx = 0;
  #pragma unroll
  for (int q = 0; q < 8; ++q) {
    int n = t + q * 256;
    float v = ub[n];
    for (int tt = 0; tt < nhist; ++tt)
      if (n == histsh[tt]) v = kNeg;
    uval[q] = v;
    if (v > lmax) { lmax = v; lidx = n; }
  }
  red[t] = lmax; redi[t] = lidx;
  __syncthreads();
  for (int off = 128; off >= 1; off >>= 1) {
    if (t < off) {
      float o = red[t + off]; int oi = redi[t + off];
      if (o > red[t] || (o == red[t] && oi < redi[t])) { red[t] = o; redi[t] = oi; }
    }
    __syncthreads();
  }
  float mu = red[0];
  int gidx = redi[0];
  __syncthreads();
  float ssum = 0.f;
  #pragma unroll
  for (int q = 0; q < 8; ++q) ssum += expf(uval[q] - mu);
  red[t] = ssum;
  __syncthreads();
  for (int off = 128; off >= 1; off >>= 1) {
    if (t < off) red[t] += red[t + off];
    __syncthreads();
  }
  float Z = red[0];
  float lse = mu + logf(Z);
  __syncthreads();
  float ent = 0.f;
  #pragma unroll
  for (int q = 0; q < 8; ++q) {
    float logp = uval[q] - lse;
    float p = expf(logp);
    if (p > 0.f) ent -= p * logp;
  }
  red[t] = ent;
  __syncthreads();
  for (int off = 128; off >= 1; off >>= 1) {
    if (t < off) red[t] += red[t + off];
    __syncthreads();
  }
  ent_out = red[0];
  gidx_out = gidx;
  lse_out = lse;
  __syncthreads();  // red/redi safe for reuse
}

// ---- fused select(t-1) + chain(t): block per (b,h), select redundant ----
__global__ __launch_bounds__(256) void k_selchain(const float* __restrict__ u,
                                                  int* __restrict__ hist,
                                                  float* __restrict__ out,
                                                  const float* __restrict__ Sacc,
                                                  const float* __restrict__ W0,
                                                  const float* __restrict__ w,
                                                  const float* __restrict__ enc,
                                                  const float* __restrict__ BT,
                                                  float* __restrict__ rpart, int tstep) {
  int b = blockIdx.x >> 3, h = blockIdx.x & 7, t = threadIdx.x;
  __shared__ float red[256];
  __shared__ int redi[256];
  __shared__ int histsh[16];
  __shared__ float sh[Dc];
  if (t < 16) histsh[t] = (t < tstep - 1) ? hist[b * 16 + t] : -1;
  __syncthreads();

  if (tstep > 0) {
    int sel_t = tstep - 1;
    int gidx; float lse, ent;
    select_core(u + (size_t)b * Nc, histsh, sel_t, t, red, redi, gidx, lse, ent);
    if (h == 0 && t == 0) {
      float pi = expf(u[(size_t)b * Nc + gidx] - lse);
      out[b * Sc + sel_t] = (float)gidx;
      out[Bc * Sc + b * Sc + sel_t] = pi;
      if (sel_t == 0) out[2 * Bc * Sc + b] = ent;
      else out[2 * Bc * Sc + b] += ent;
      hist[b * 16 + sel_t] = gidx;
    }
    if (t == 0) histsh[sel_t] = gidx;
    __syncthreads();
  }

  // chain for own head
  float se = Sacc[((size_t)b * Hc + h) * Dc + t];
  float Wh = W0[b * Hc + h];
  for (int tt = 0; tt < tstep; ++tt) {
    int j = histsh[tt];
    float wv = w[((size_t)b * Hc + h) * Nc + j];
    se -= wv * enc[((size_t)b * Nc + j) * Dc + t];
    Wh -= wv;
  }
  sh[t] = se / Wh;
  __syncthreads();
  const float* bt = BT + (size_t)h * Dc * Dc + t;
  float a0 = 0.f, a1 = 0.f, a2 = 0.f, a3 = 0.f;
  #pragma unroll 4
  for (int e = 0; e < Dc; e += 4) {
    a0 += bt[(size_t)e * Dc] * sh[e];
    a1 += bt[(size_t)(e + 1) * Dc] * sh[e + 1];
    a2 += bt[(size_t)(e + 2) * Dc] * sh[e + 2];
    a3 += bt[(size_t)(e + 3) * Dc] * sh[e + 3];
  }
  rpart[((size_t)b * Hc + h) * Dc + t] = (a0 + a1) + (a2 + a3);
}

// ---- u scores: row-per-thread, rpart reduction folded ----
__global__ __launch_bounds__(256) void k_uscore(const float* __restrict__ enc,
                                                const float* __restrict__ rpart,
                                                const float* __restrict__ cvec,
                                                float* __restrict__ u) {
  int b = blockIdx.x >> 3, nt = blockIdx.x & 7, t = threadIdx.x;
  int n = nt * 256 + t;
  __shared__ __align__(16) float rsm[Dc];
  {
    float vsum = cvec[t];
    #pragma unroll
    for (int h = 0; h < Hc; ++h) vsum += rpart[((size_t)b * Hc + h) * Dc + t];
    rsm[t] = vsum;
  }
  __syncthreads();
  const float4* row = reinterpret_cast<const float4*>(enc + ((size_t)b * Nc + n) * Dc);
  float acc = 0.f;
  #pragma unroll 16
  for (int d4 = 0; d4 < 64; ++d4) {
    const float4 e = row[d4];
    const float4 rr = *reinterpret_cast<const float4*>(rsm + d4 * 4);
    acc += e.x * rr.x + e.y * rr.y + e.z * rr.z + e.w * rr.w;
  }
  u[(size_t)b * Nc + n] = kClip * tanhf(kScale2 * acc);
}

// ---- final select (step Sc-1) ----
__global__ __launch_bounds__(256) void k_selfinal(const float* __restrict__ u,
                                                  const int* __restrict__ hist,
                                                  float* __restrict__ out) {
  int b = blockIdx.x, t = threadIdx.x;
  __shared__ float red[256];
  __shared__ int redi[256];
  __shared__ int histsh[16];
  if (t < 16) histsh[t] = (t < Sc - 1) ? hist[b * 16 + t] : -1;
  __syncthreads();
  int gidx; float lse, ent;
  select_core(u + (size_t)b * Nc, histsh, Sc - 1, t, red, redi, gidx, lse, ent);
  if (t == 0) {
    float pi = expf(u[(size_t)b * Nc + gidx] - lse);
    out[b * Sc + (Sc - 1)] = (float)gidx;
    out[Bc * Sc + b * Sc + (Sc - 1)] = pi;
    out[2 * Bc * Sc + b] += ent;
  }
}

extern "C" void kernel_launch(void* const* d_in, const int* in_sizes, int n_in,
                              void* d_out, int out_size, void* d_ws, size_t ws_size,
                              hipStream_t stream) {
  (void)in_sizes; (void)n_in; (void)out_size; (void)ws_size;
  const float* enc  = (const float*)d_in[0];
  const float* in_w = (const float*)d_in[1];
  const float* in_b = (const float*)d_in[2];
  const float* ow   = (const float*)d_in[3];
  const float* ob   = (const float*)d_in[4];
  const float* swq  = (const float*)d_in[5];
  const float* swk  = (const float*)d_in[6];
  float* out = (float*)d_out;

  float* ws = (float*)d_ws;
  size_t off = 0;
  auto alloc = [&](size_t n) { float* p = ws + off; off += n; return p; };
  float* hpart = alloc((size_t)Bc * 8 * Dc);
  float* g     = alloc((size_t)Bc * Hc * Dc);
  float* c     = alloc((size_t)Bc * Hc);
  float* s     = alloc((size_t)Bc * Hc * Nc);
  float* mrow  = alloc((size_t)Bc * Hc);
  float* w     = alloc((size_t)Bc * Hc * Nc);
  float* W0    = alloc((size_t)Bc * Hc);
  float* Spart = alloc((size_t)Bc * 8 * Hc * Dc);
  float* Sacc  = alloc((size_t)Bc * Hc * Dc);
  float* M1    = alloc((size_t)Dc * Dc);
  float* m1b   = alloc(Dc);
  float* Aout  = alloc((size_t)Dc * Dc);
  float* cvec  = alloc(Dc);
  float* BT    = alloc((size_t)Hc * Dc * Dc);
  float* rpart = alloc((size_t)Bc * Hc * Dc);
  float* u     = alloc((size_t)Bc * Nc);
  int* hist    = (int*)alloc((size_t)Bc * 16);

  k_hmean_part<<<Bc * 8, 256, 0, stream>>>(enc, hpart);
  k_qgc<<<Bc, 256, 0, stream>>>(hpart, in_w, in_b, g, c);
  k_A1<<<Dc, 256, 0, stream>>>(swq, ow, ob, M1, m1b);
  k_A2<<<Dc, 256, 0, stream>>>(swk, M1, m1b, in_b, Aout, cvec);
  k_A3<<<Hc * 8, 256, 0, stream>>>(Aout, in_w, BT);
  k_scores<<<Bc * 8, 256, 0, stream>>>(enc, g, c, s);
  k_rowmax<<<Bc * Hc, 256, 0, stream>>>(s, mrow);
  k_S0part<<<Bc * 8, 256, 0, stream>>>(enc, s, mrow, w, Spart);
  k_S0red<<<Bc * Hc, 256, 0, stream>>>(Spart, w, Sacc, W0);

  for (int t = 0; t < Sc; ++t) {
    k_selchain<<<Bc * Hc, 256, 0, stream>>>(u, hist, out, Sacc, W0, w, enc, BT, rpart, t);
    k_uscore<<<Bc * 8, 256, 0, stream>>>(enc, rpart, cvec, u);
  }
  k_selfinal<<<Bc, 256, 0, stream>>>(u, hist, out);
}

// Round 5
// 503.384 us; speedup vs baseline: 2.7271x; 1.1246x over previous
//
#include <hip/hip_runtime.h>
#include <hip/hip_bf16.h>
#include <math.h>

namespace {
constexpr int Bc = 64, Nc = 2048, Dc = 256, Hc = 8, DHc = 32, Sc = 10;
constexpr float kNeg = -1000000000.0f;
constexpr float kClip = 10.0f;
constexpr float kScale = 0.17677669529663687f;   // 1/sqrt(32)
constexpr float kScale2 = 0.0625f;               // 1/sqrt(256)
}

// ---- h_mean partials: 2048 blocks, 64-row chunks ----
__global__ __launch_bounds__(256) void k_hmean_part(const float* __restrict__ enc,
                                                    float* __restrict__ hpart) {
  int b = blockIdx.x >> 5, c = blockIdx.x & 31, d = threadIdx.x;
  const float* p = enc + ((size_t)b * Nc + c * 64) * Dc + d;
  float s = 0.f;
  #pragma unroll 8
  for (int n = 0; n < 64; ++n) s += p[(size_t)n * Dc];
  hpart[(size_t)blockIdx.x * Dc + d] = s;
}

// ---- qgc (folds hmean reduction): q, g, c ----
__global__ __launch_bounds__(256) void k_qgc(const float* __restrict__ hpart,
                                             const float* __restrict__ w_in,
                                             const float* __restrict__ b_in,
                                             float* __restrict__ g, float* __restrict__ c) {
  int b = blockIdx.x, t = threadIdx.x;
  __shared__ float hm[Dc];
  __shared__ float qsh[Dc];
  {
    float s = 0.f;
    for (int cc = 0; cc < 32; ++cc) s += hpart[(size_t)(b * 32 + cc) * Dc + t];
    hm[t] = s * (1.0f / Nc);
  }
  __syncthreads();
  {
    const float* row = w_in + (size_t)t * Dc;  // Wq row t
    float acc = b_in[t];
    for (int d = 0; d < Dc; ++d) acc += row[d] * hm[d];
    qsh[t] = acc;
  }
  __syncthreads();
  for (int h = 0; h < Hc; ++h) {
    float acc = 0.f;
    const float* wk = w_in + (size_t)(Dc + h * DHc) * Dc + t;  // Wk rows, col t
    const float* qh = qsh + h * DHc;
    #pragma unroll 8
    for (int i = 0; i < DHc; ++i) acc += qh[i] * wk[(size_t)i * Dc];
    g[((size_t)b * Hc + h) * Dc + t] = acc;
  }
  if (t < Hc) {
    float acc = 0.f;
    for (int i = 0; i < DHc; ++i) acc += qsh[t * DHc + i] * b_in[Dc + t * DHc + i];
    c[b * Hc + t] = acc;
  }
}

// ---- setup: M1 = sha_wq @ out_w ; m1b = sha_wq @ out_b ----
__global__ __launch_bounds__(256) void k_A1(const float* __restrict__ swq,
                                            const float* __restrict__ ow,
                                            const float* __restrict__ ob,
                                            float* __restrict__ M1, float* __restrict__ m1b) {
  int i = blockIdx.x, e = threadIdx.x;
  __shared__ float row[Dc];
  __shared__ float red[256];
  row[e] = swq[(size_t)i * Dc + e];
  __syncthreads();
  float acc = 0.f;
  #pragma unroll 4
  for (int k = 0; k < Dc; ++k) acc += row[k] * ow[(size_t)k * Dc + e];
  M1[(size_t)i * Dc + e] = acc;
  red[e] = row[e] * ob[e];
  __syncthreads();
  for (int off = 128; off >= 1; off >>= 1) {
    if (e < off) red[e] += red[e + off];
    __syncthreads();
  }
  if (e == 0) m1b[i] = red[0];
}

// ---- setup: A = sha_wk^T @ M1 ; cvec = A@bv + sha_wk^T@m1b ----
__global__ __launch_bounds__(256) void k_A2(const float* __restrict__ swk,
                                            const float* __restrict__ M1,
                                            const float* __restrict__ m1b,
                                            const float* __restrict__ b_in,
                                            float* __restrict__ Aout, float* __restrict__ cvec) {
  int d = blockIdx.x, e = threadIdx.x;
  __shared__ float col[Dc];
  __shared__ float red[256];
  col[e] = swk[(size_t)e * Dc + d];
  __syncthreads();
  float acc = 0.f;
  #pragma unroll 4
  for (int k = 0; k < Dc; ++k) acc += col[k] * M1[(size_t)k * Dc + e];
  Aout[(size_t)d * Dc + e] = acc;
  red[e] = acc * b_in[2 * Dc + e] + col[e] * m1b[e];
  __syncthreads();
  for (int off = 128; off >= 1; off >>= 1) {
    if (e < off) red[e] += red[e + off];
    __syncthreads();
  }
  if (e == 0) cvec[d] = red[0];
}

// ---- setup: BT[(h*256+e)*256+d] = sum_i A[d][h*32+i] * Wv[h*32+i][e] ----
__global__ __launch_bounds__(256) void k_A3(const float* __restrict__ Aout,
                                            const float* __restrict__ w_in,
                                            float* __restrict__ BT) {
  int h = blockIdx.x >> 3, et = blockIdx.x & 7, d = threadIdx.x;
  float arow[DHc];
  #pragma unroll
  for (int i = 0; i < DHc; ++i) arow[i] = Aout[(size_t)d * Dc + h * DHc + i];
  __shared__ float wv[DHc][DHc];
  for (int k = threadIdx.x; k < DHc * DHc; k += 256) {
    int i = k >> 5, j = k & 31;
    wv[i][j] = w_in[(size_t)(2 * Dc + h * DHc + i) * Dc + et * DHc + j];
  }
  __syncthreads();
  for (int j = 0; j < DHc; ++j) {
    float acc = 0.f;
    #pragma unroll
    for (int i = 0; i < DHc; ++i) acc += arow[i] * wv[i][j];
    BT[((size_t)h * Dc + et * DHc + j) * Dc + d] = acc;
  }
}

// ---- scores: 2 threads per row, 1024 blocks ----
__global__ __launch_bounds__(256) void k_scores(const float* __restrict__ enc,
                                                const float* __restrict__ g,
                                                const float* __restrict__ c,
                                                float* __restrict__ s) {
  int b = blockIdx.x >> 4, nt = blockIdx.x & 15, t = threadIdx.x;
  __shared__ __align__(16) float gsm[Hc * Dc];
  __shared__ float csm[Hc];
  for (int k = t; k < Hc * Dc; k += 256) gsm[k] = g[(size_t)b * Hc * Dc + k];
  if (t < Hc) csm[t] = c[b * Hc + t];
  __syncthreads();
  int row = t >> 1, half = t & 1;
  int n = nt * 128 + row;
  const float4* rowp = reinterpret_cast<const float4*>(enc + ((size_t)b * Nc + n) * Dc);
  float acc[Hc] = {};
  #pragma unroll 8
  for (int i = 0; i < 32; ++i) {
    int d4 = i * 2 + half;
    const float4 e = rowp[d4];
    #pragma unroll
    for (int h = 0; h < Hc; ++h) {
      const float4 g4 = *reinterpret_cast<const float4*>(gsm + h * Dc + d4 * 4);
      acc[h] += e.x * g4.x + e.y * g4.y + e.z * g4.z + e.w * g4.w;
    }
  }
  #pragma unroll
  for (int h = 0; h < Hc; ++h) acc[h] += __shfl_xor(acc[h], 1);
  if (half == 0) {
    #pragma unroll
    for (int h = 0; h < Hc; ++h)
      s[((size_t)b * Hc + h) * Nc + n] = kScale * (acc[h] + csm[h]);
  }
}

// ---- rowmax per (b,h) ----
__global__ __launch_bounds__(256) void k_rowmax(const float* __restrict__ s,
                                                float* __restrict__ mrow) {
  int bh = blockIdx.x, t = threadIdx.x;
  __shared__ float red[256];
  float m = -3.0e38f;
  #pragma unroll
  for (int q = 0; q < 8; ++q) m = fmaxf(m, s[(size_t)bh * Nc + q * 256 + t]);
  red[t] = m;
  __syncthreads();
  for (int off = 128; off >= 1; off >>= 1) {
    if (t < off) red[t] = fmaxf(red[t], red[t + off]);
    __syncthreads();
  }
  if (t == 0) mrow[bh] = red[0];
}

// ---- S0 partials (+exp fold: w = exp(s-m)) ----
__global__ __launch_bounds__(256) void k_S0part(const float* __restrict__ enc,
                                                const float* __restrict__ s,
                                                const float* __restrict__ mrow,
                                                float* __restrict__ w,
                                                float* __restrict__ Spart) {
  int b = blockIdx.x >> 3, cid = blockIdx.x & 7, t = threadIdx.x;
  __shared__ float wsm[Hc * 256];
  #pragma unroll
  for (int h = 0; h < Hc; ++h) {
    float m = mrow[b * Hc + h];
    float e = expf(s[((size_t)b * Hc + h) * Nc + cid * 256 + t] - m);
    wsm[h * 256 + t] = e;
    w[((size_t)b * Hc + h) * Nc + cid * 256 + t] = e;
  }
  __syncthreads();
  float acc[Hc] = {};
  const float* ep = enc + ((size_t)b * Nc + cid * 256) * Dc + t;
  for (int ni = 0; ni < 256; ++ni) {
    float ev = ep[(size_t)ni * Dc];
    #pragma unroll
    for (int h = 0; h < Hc; ++h) acc[h] += wsm[h * 256 + ni] * ev;
  }
  #pragma unroll
  for (int h = 0; h < Hc; ++h)
    Spart[(((size_t)b * 8 + cid) * Hc + h) * Dc + t] = acc[h];
}

// ---- S0 reduce + W0 = sum_n w ----
__global__ __launch_bounds__(256) void k_S0red(const float* __restrict__ Spart,
                                               const float* __restrict__ w,
                                               float* __restrict__ Sacc,
                                               float* __restrict__ W0) {
  int b = blockIdx.x >> 3, h = blockIdx.x & 7, t = threadIdx.x;
  __shared__ float red[256];
  float acc = 0.f;
  for (int cid = 0; cid < 8; ++cid)
    acc += Spart[(((size_t)b * 8 + cid) * Hc + h) * Dc + t];
  Sacc[((size_t)b * Hc + h) * Dc + t] = acc;
  float ws = 0.f;
  #pragma unroll
  for (int q = 0; q < 8; ++q) ws += w[((size_t)b * Hc + h) * Nc + q * 256 + t];
  red[t] = ws;
  __syncthreads();
  for (int off = 128; off >= 1; off >>= 1) {
    if (t < off) red[t] += red[t + off];
    __syncthreads();
  }
  if (t == 0) W0[b * Hc + h] = red[0];
}

// ---- shared select core: masked log-softmax + argmax + entropy ----
__device__ __forceinline__ void select_core(const float* __restrict__ ub,
                                            const int* histsh, int nhist, int t,
                                            float* red, int* redi,
                                            int& gidx_out, float& lse_out, float& ent_out) {
  float uval[8];
  float lmax = -3.0e38f;
  int lidx = 0;
  #pragma unroll
  for (int q = 0; q < 8; ++q) {
    int n = t + q * 256;
    float v = ub[n];
    for (int tt = 0; tt < nhist; ++tt)
      if (n == histsh[tt]) v = kNeg;
    uval[q] = v;
    if (v > lmax) { lmax = v; lidx = n; }
  }
  red[t] = lmax; redi[t] = lidx;
  __syncthreads();
  for (int off = 128; off >= 1; off >>= 1) {
    if (t < off) {
      float o = red[t + off]; int oi = redi[t + off];
      if (o > red[t] || (o == red[t] && oi < redi[t])) { red[t] = o; redi[t] = oi; }
    }
    __syncthreads();
  }
  float mu = red[0];
  int gidx = redi[0];
  __syncthreads();
  float ssum = 0.f;
  #pragma unroll
  for (int q = 0; q < 8; ++q) ssum += expf(uval[q] - mu);
  red[t] = ssum;
  __syncthreads();
  for (int off = 128; off >= 1; off >>= 1) {
    if (t < off) red[t] += red[t + off];
    __syncthreads();
  }
  float Z = red[0];
  float lse = mu + logf(Z);
  __syncthreads();
  float ent = 0.f;
  #pragma unroll
  for (int q = 0; q < 8; ++q) {
    float logp = uval[q] - lse;
    float p = expf(logp);
    if (p > 0.f) ent -= p * logp;
  }
  red[t] = ent;
  __syncthreads();
  for (int off = 128; off >= 1; off >>= 1) {
    if (t < off) red[t] += red[t + off];
    __syncthreads();
  }
  ent_out = red[0];
  gidx_out = gidx;
  lse_out = lse;
  __syncthreads();  // red/redi safe for reuse
}

// ---- fused select(t-1) + chain(t): block per (b,h), select redundant ----
__global__ __launch_bounds__(256) void k_selchain(const float* __restrict__ u,
                                                  int* __restrict__ hist,
                                                  float* __restrict__ out,
                                                  const float* __restrict__ Sacc,
                                                  const float* __restrict__ W0,
                                                  const float* __restrict__ w,
                                                  const float* __restrict__ enc,
                                                  const float* __restrict__ BT,
                                                  float* __restrict__ rpart, int tstep) {
  int b = blockIdx.x >> 3, h = blockIdx.x & 7, t = threadIdx.x;
  __shared__ float red[256];
  __shared__ int redi[256];
  __shared__ int histsh[16];
  __shared__ float sh[Dc];
  if (t < 16) histsh[t] = (t < tstep - 1) ? hist[b * 16 + t] : -1;
  __syncthreads();

  if (tstep > 0) {
    int sel_t = tstep - 1;
    int gidx; float lse, ent;
    select_core(u + (size_t)b * Nc, histsh, sel_t, t, red, redi, gidx, lse, ent);
    if (h == 0 && t == 0) {
      float pi = expf(u[(size_t)b * Nc + gidx] - lse);
      out[b * Sc + sel_t] = (float)gidx;
      out[Bc * Sc + b * Sc + sel_t] = pi;
      if (sel_t == 0) out[2 * Bc * Sc + b] = ent;
      else out[2 * Bc * Sc + b] += ent;
      hist[b * 16 + sel_t] = gidx;
    }
    if (t == 0) histsh[sel_t] = gidx;
    __syncthreads();
  }

  // chain for own head
  float se = Sacc[((size_t)b * Hc + h) * Dc + t];
  float Wh = W0[b * Hc + h];
  for (int tt = 0; tt < tstep; ++tt) {
    int j = histsh[tt];
    float wv = w[((size_t)b * Hc + h) * Nc + j];
    se -= wv * enc[((size_t)b * Nc + j) * Dc + t];
    Wh -= wv;
  }
  sh[t] = se / Wh;
  __syncthreads();
  const float* bt = BT + (size_t)h * Dc * Dc + t;
  float a0 = 0.f, a1 = 0.f, a2 = 0.f, a3 = 0.f;
  #pragma unroll 4
  for (int e = 0; e < Dc; e += 4) {
    a0 += bt[(size_t)e * Dc] * sh[e];
    a1 += bt[(size_t)(e + 1) * Dc] * sh[e + 1];
    a2 += bt[(size_t)(e + 2) * Dc] * sh[e + 2];
    a3 += bt[(size_t)(e + 3) * Dc] * sh[e + 3];
  }
  rpart[((size_t)b * Hc + h) * Dc + t] = (a0 + a1) + (a2 + a3);
}

// ---- u scores: 4 threads per row, 2048 blocks ----
__global__ __launch_bounds__(256) void k_uscore(const float* __restrict__ enc,
                                                const float* __restrict__ rpart,
                                                const float* __restrict__ cvec,
                                                float* __restrict__ u) {
  int b = blockIdx.x >> 5, ng = blockIdx.x & 31, t = threadIdx.x;
  __shared__ __align__(16) float rsm[Dc];
  {
    float vsum = cvec[t];
    #pragma unroll
    for (int h = 0; h < Hc; ++h) vsum += rpart[((size_t)b * Hc + h) * Dc + t];
    rsm[t] = vsum;
  }
  __syncthreads();
  int row = t >> 2, q = t & 3;
  int n = ng * 64 + row;
  const float4* rowp = reinterpret_cast<const float4*>(enc + ((size_t)b * Nc + n) * Dc);
  const float4* r4 = reinterpret_cast<const float4*>(rsm);
  float acc = 0.f;
  #pragma unroll
  for (int i = 0; i < 16; ++i) {
    int d4 = i * 4 + q;
    const float4 e = rowp[d4];
    const float4 rr = r4[d4];
    acc += e.x * rr.x + e.y * rr.y + e.z * rr.z + e.w * rr.w;
  }
  acc += __shfl_xor(acc, 1);
  acc += __shfl_xor(acc, 2);
  if (q == 0) u[(size_t)b * Nc + n] = kClip * tanhf(kScale2 * acc);
}

// ---- final select (step Sc-1) ----
__global__ __launch_bounds__(256) void k_selfinal(const float* __restrict__ u,
                                                  const int* __restrict__ hist,
                                                  float* __restrict__ out) {
  int b = blockIdx.x, t = threadIdx.x;
  __shared__ float red[256];
  __shared__ int redi[256];
  __shared__ int histsh[16];
  if (t < 16) histsh[t] = (t < Sc - 1) ? hist[b * 16 + t] : -1;
  __syncthreads();
  int gidx; float lse, ent;
  select_core(u + (size_t)b * Nc, histsh, Sc - 1, t, red, redi, gidx, lse, ent);
  if (t == 0) {
    float pi = expf(u[(size_t)b * Nc + gidx] - lse);
    out[b * Sc + (Sc - 1)] = (float)gidx;
    out[Bc * Sc + b * Sc + (Sc - 1)] = pi;
    out[2 * Bc * Sc + b] += ent;
  }
}

extern "C" void kernel_launch(void* const* d_in, const int* in_sizes, int n_in,
                              void* d_out, int out_size, void* d_ws, size_t ws_size,
                              hipStream_t stream) {
  (void)in_sizes; (void)n_in; (void)out_size; (void)ws_size;
  const float* enc  = (const float*)d_in[0];
  const float* in_w = (const float*)d_in[1];
  const float* in_b = (const float*)d_in[2];
  const float* ow   = (const float*)d_in[3];
  const float* ob   = (const float*)d_in[4];
  const float* swq  = (const float*)d_in[5];
  const float* swk  = (const float*)d_in[6];
  float* out = (float*)d_out;

  float* ws = (float*)d_ws;
  size_t off = 0;
  auto alloc = [&](size_t n) { float* p = ws + off; off += n; return p; };
  float* hpart = alloc((size_t)Bc * 32 * Dc);
  float* g     = alloc((size_t)Bc * Hc * Dc);
  float* c     = alloc((size_t)Bc * Hc);
  float* s     = alloc((size_t)Bc * Hc * Nc);
  float* mrow  = alloc((size_t)Bc * Hc);
  float* w     = alloc((size_t)Bc * Hc * Nc);
  float* W0    = alloc((size_t)Bc * Hc);
  float* Spart = alloc((size_t)Bc * 8 * Hc * Dc);
  float* Sacc  = alloc((size_t)Bc * Hc * Dc);
  float* M1    = alloc((size_t)Dc * Dc);
  float* m1b   = alloc(Dc);
  float* Aout  = alloc((size_t)Dc * Dc);
  float* cvec  = alloc(Dc);
  float* BT    = alloc((size_t)Hc * Dc * Dc);
  float* rpart = alloc((size_t)Bc * Hc * Dc);
  float* u     = alloc((size_t)Bc * Nc);
  int* hist    = (int*)alloc((size_t)Bc * 16);

  k_hmean_part<<<Bc * 32, 256, 0, stream>>>(enc, hpart);
  k_qgc<<<Bc, 256, 0, stream>>>(hpart, in_w, in_b, g, c);
  k_A1<<<Dc, 256, 0, stream>>>(swq, ow, ob, M1, m1b);
  k_A2<<<Dc, 256, 0, stream>>>(swk, M1, m1b, in_b, Aout, cvec);
  k_A3<<<Hc * 8, 256, 0, stream>>>(Aout, in_w, BT);
  k_scores<<<Bc * 16, 256, 0, stream>>>(enc, g, c, s);
  k_rowmax<<<Bc * Hc, 256, 0, stream>>>(s, mrow);
  k_S0part<<<Bc * 8, 256, 0, stream>>>(enc, s, mrow, w, Spart);
  k_S0red<<<Bc * Hc, 256, 0, stream>>>(Spart, w, Sacc, W0);

  for (int t = 0; t < Sc; ++t) {
    k_selchain<<<Bc * Hc, 256, 0, stream>>>(u, hist, out, Sacc, W0, w, enc, BT, rpart, t);
    k_uscore<<<Bc * 32, 256, 0, stream>>>(enc, rpart, cvec, u);
  }
  k_selfinal<<<Bc, 256, 0, stream>>>(u, hist, out);
}